// Round 4
// baseline (5377.621 us; speedup 1.0000x reference)
//
#include <hip/hip_runtime.h>

typedef __bf16 bf16x8 __attribute__((ext_vector_type(8)));
typedef float f32x4 __attribute__((ext_vector_type(4)));

#define T_STEPS 512

__device__ __forceinline__ float fsig(float v) { return 1.0f / (1.0f + __expf(-v)); }
__device__ __forceinline__ float ftanhf(float v) {
    float a = fminf(fmaxf(v, -15.0f), 15.0f);
    float e = __expf(2.0f * a);
    return (e - 1.0f) / (e + 1.0f);
}
__device__ __forceinline__ unsigned short f2bfu(float f) {
    unsigned u = __float_as_uint(f);
    u += 0x7fffu + ((u >> 16) & 1u);
    return (unsigned short)(u >> 16);
}
__device__ __forceinline__ bf16x8 cvt8(float4 a, float4 b) {
    bf16x8 f;
    f[0] = (__bf16)a.x; f[1] = (__bf16)a.y; f[2] = (__bf16)a.z; f[3] = (__bf16)a.w;
    f[4] = (__bf16)b.x; f[5] = (__bf16)b.y; f[6] = (__bf16)b.z; f[7] = (__bf16)b.w;
    return f;
}

// Coherent (cross-XCD) access helpers: per-access LLC coherence, NO cache-sweep
// fences. sc0 sc1 loads = forced miss past L1/L2 (read the LLC coherence
// point); sc0 sc1 stores = write-through (no dirty L2 line left behind).
__device__ __forceinline__ void load_hb8(const unsigned short* p, uint4* f) {
    asm volatile(
        "global_load_dwordx4 %0, %8, off sc0 sc1\n\t"
        "global_load_dwordx4 %1, %8, off offset:64 sc0 sc1\n\t"
        "global_load_dwordx4 %2, %8, off offset:128 sc0 sc1\n\t"
        "global_load_dwordx4 %3, %8, off offset:192 sc0 sc1\n\t"
        "global_load_dwordx4 %4, %8, off offset:256 sc0 sc1\n\t"
        "global_load_dwordx4 %5, %8, off offset:320 sc0 sc1\n\t"
        "global_load_dwordx4 %6, %8, off offset:384 sc0 sc1\n\t"
        "global_load_dwordx4 %7, %8, off offset:448 sc0 sc1\n\t"
        "s_waitcnt vmcnt(0)"
        : "=&v"(f[0]), "=&v"(f[1]), "=&v"(f[2]), "=&v"(f[3]),
          "=&v"(f[4]), "=&v"(f[5]), "=&v"(f[6]), "=&v"(f[7])
        : "v"(p)
        : "memory");
}
__device__ __forceinline__ void store_hb(unsigned short* p, unsigned short v) {
    unsigned int vv = v;
    asm volatile("global_store_short %0, %1, off sc0 sc1"
                 :: "v"(p), "v"(vv) : "memory");
}
__device__ __forceinline__ void vm_drain() {
    asm volatile("s_waitcnt vmcnt(0)" ::: "memory");
}

// Persistent LSTM: 256 blocks (1/CU) x 512 threads (8 waves).
// Block (bg,cg): bg = batch group (16 rows), cg = h-col group (16 cols x 4 gates).
// Waves 0-3 (cell waves): W_ih fragments; produce x-projection partials for
//   step t+1 off the critical path; consume h via LDS and write fp32 outputs.
// Waves 4-7 (h waves): W_hh fragments; own the FULL critical path:
//   poll counter -> coherent h load -> MFMA -> reduce -> gates -> c update ->
//   coherent h store -> fire-and-forget atomicAdd arrival.
// Barrier: per-bg monotonic atomic counter at the LLC (64 blocks x 4 waves add
//   1/step -> target 256*t), polled by ONE lane per block, LDS-broadcast.
__global__ __launch_bounds__(512, 2) void lstm_persist(
    const float* __restrict__ x, const float* __restrict__ h0,
    const float* __restrict__ c0, const float* __restrict__ w_ih,
    const float* __restrict__ w_hh, const float* __restrict__ b_ih,
    const float* __restrict__ b_hh, float* __restrict__ out,
    unsigned short* __restrict__ hb, int* __restrict__ cnt_base)
{
    const int tid  = threadIdx.x;
    const int wave = tid >> 6;
    const int lane = tid & 63;
    const int bid  = blockIdx.x;
    const int bg   = bid >> 6;   // 0..3
    const int cg   = bid & 63;   // 0..63
    const int colbase = cg << 4;
    const int batbase = bg << 4;

    __shared__ float xred[2][4][4][4][64];  // [buf][wave][gate][reg][lane] 32 KB
    __shared__ float hredLDS[4][4][4][64];  // [hwave][gate][reg][lane]     16 KB
    __shared__ float hout[256];             // h values for cell waves       1 KB
    __shared__ int go;                      // LDS broadcast of barrier pass

    const int quad = lane >> 4;
    const int l15  = lane & 15;

    int* cnt = cnt_base + (bg << 5);   // per-bg counter, 128 B apart

    // ---------- one-time weight preload into registers (bf16) ----------
    bf16x8 bw[8][4];
    {
        const float* wsrc = (wave < 4) ? w_ih : w_hh;
        const int koff = (wave & 3) * 256 + quad * 8;
        #pragma unroll
        for (int n = 0; n < 4; ++n) {
            const float* prow = wsrc + (size_t)((n << 10) + colbase + l15) * 1024 + koff;
            #pragma unroll
            for (int kk = 0; kk < 8; ++kk) {
                float4 a = *(const float4*)(prow + kk * 32);
                float4 b = *(const float4*)(prow + kk * 32 + 4);
                bw[kk][n] = cvt8(a, b);
            }
        }
    }

    // Cell coordinates: cv = reg-slice (h waves: wave-4; cell waves: tid>>6).
    const int cv = (tid >> 6) & 3;
    const int cellrow  = ((lane >> 4) << 2) + cv;
    const int cellcolg = colbase + l15;
    const int cellb    = batbase + cellrow;

    // ---------- h-wave persistent cell state ----------
    float creg = 0.0f, bias0 = 0.f, bias1 = 0.f, bias2 = 0.f, bias3 = 0.f;
    if (wave >= 4) {
        creg  = c0[cellb * 1024 + cellcolg];
        bias0 = b_ih[cellcolg]        + b_hh[cellcolg];
        bias1 = b_ih[1024 + cellcolg] + b_hh[1024 + cellcolg];
        bias2 = b_ih[2048 + cellcolg] + b_hh[2048 + cellcolg];
        bias3 = b_ih[3072 + cellcolg] + b_hh[3072 + cellcolg];
    }
    if (tid == 256) __hip_atomic_store(&go, 0, __ATOMIC_RELAXED,
                                       __HIP_MEMORY_SCOPE_WORKGROUP);

    float* outp = out;
    float* hnp  = out + (size_t)64 * 512 * 1024;
    float* cnp  = hnp + 64 * 1024;

    const int abatch = batbase + l15;   // A-operand row = batch

    // x prefetch registers (cell waves only; dead for h waves)
    float4 pa[8], pb[8];

    // ---------- preamble (cell waves): x-proj for t=0 into xred[0], prefetch t=1
    if (wave < 4) {
        const float* px = x + ((size_t)abatch * 512 + 0) * 1024 + wave * 256 + quad * 8;
        f32x4 xacc[4];
        #pragma unroll
        for (int n = 0; n < 4; ++n) xacc[n] = (f32x4){0.f, 0.f, 0.f, 0.f};
        #pragma unroll
        for (int kk = 0; kk < 8; ++kk) {
            float4 a = *(const float4*)(px + kk * 32);
            float4 b = *(const float4*)(px + kk * 32 + 4);
            bf16x8 af = cvt8(a, b);
            xacc[0] = __builtin_amdgcn_mfma_f32_16x16x32_bf16(af, bw[kk][0], xacc[0], 0, 0, 0);
            xacc[1] = __builtin_amdgcn_mfma_f32_16x16x32_bf16(af, bw[kk][1], xacc[1], 0, 0, 0);
            xacc[2] = __builtin_amdgcn_mfma_f32_16x16x32_bf16(af, bw[kk][2], xacc[2], 0, 0, 0);
            xacc[3] = __builtin_amdgcn_mfma_f32_16x16x32_bf16(af, bw[kk][3], xacc[3], 0, 0, 0);
        }
        #pragma unroll
        for (int n = 0; n < 4; ++n)
            #pragma unroll
            for (int v = 0; v < 4; ++v)
                xred[0][wave][n][v][lane] = xacc[n][v];
        const float* pn = x + ((size_t)abatch * 512 + 1) * 1024 + wave * 256 + quad * 8;
        #pragma unroll
        for (int kk = 0; kk < 8; ++kk) {
            pa[kk] = *(const float4*)(pn + kk * 32);
            pb[kk] = *(const float4*)(pn + kk * 32 + 4);
        }
    }

    for (int t = 0; t < T_STEPS; ++t) {
        // ---------- h waves: critical path ----------
        if (wave >= 4) {
            f32x4 acc[4];
            #pragma unroll
            for (int n = 0; n < 4; ++n) acc[n] = (f32x4){0.f, 0.f, 0.f, 0.f};

            if (t == 0) {
                const float* ph = h0 + abatch * 1024 + (wave & 3) * 256 + quad * 8;
                #pragma unroll
                for (int kk = 0; kk < 8; ++kk) {
                    float4 a = *(const float4*)(ph + kk * 32);
                    float4 b = *(const float4*)(ph + kk * 32 + 4);
                    bf16x8 af = cvt8(a, b);
                    acc[0] = __builtin_amdgcn_mfma_f32_16x16x32_bf16(af, bw[kk][0], acc[0], 0, 0, 0);
                    acc[1] = __builtin_amdgcn_mfma_f32_16x16x32_bf16(af, bw[kk][1], acc[1], 0, 0, 0);
                    acc[2] = __builtin_amdgcn_mfma_f32_16x16x32_bf16(af, bw[kk][2], acc[2], 0, 0, 0);
                    acc[3] = __builtin_amdgcn_mfma_f32_16x16x32_bf16(af, bw[kk][3], acc[3], 0, 0, 0);
                }
            } else {
                const int target = t << 8;   // 256*t
                if (wave == 4) {
                    // single-lane global poll, wave-uniform via readfirstlane
                    for (;;) {
                        int p = 0;
                        if (lane == 0)
                            p = __hip_atomic_load(cnt, __ATOMIC_RELAXED,
                                                  __HIP_MEMORY_SCOPE_AGENT);
                        p = __builtin_amdgcn_readfirstlane(p);
                        if (p >= target) break;
                        __builtin_amdgcn_s_sleep(1);
                    }
                    if (lane == 0)
                        __hip_atomic_store(&go, t, __ATOMIC_RELAXED,
                                           __HIP_MEMORY_SCOPE_WORKGROUP);
                } else {
                    // cheap LDS spin (same address: broadcast, no global traffic)
                    while (__hip_atomic_load(&go, __ATOMIC_RELAXED,
                                             __HIP_MEMORY_SCOPE_WORKGROUP) < t) {
                        __builtin_amdgcn_s_sleep(1);
                    }
                }
                const unsigned short* ph = hb + ((t - 1) & 1) * 65536
                                             + abatch * 1024 + (wave & 3) * 256 + quad * 8;
                uint4 fr[8];
                load_hb8(ph, fr);
                #pragma unroll
                for (int kk = 0; kk < 8; ++kk) {
                    union { uint4 u; bf16x8 v; } cc;
                    cc.u = fr[kk];
                    acc[0] = __builtin_amdgcn_mfma_f32_16x16x32_bf16(cc.v, bw[kk][0], acc[0], 0, 0, 0);
                    acc[1] = __builtin_amdgcn_mfma_f32_16x16x32_bf16(cc.v, bw[kk][1], acc[1], 0, 0, 0);
                    acc[2] = __builtin_amdgcn_mfma_f32_16x16x32_bf16(cc.v, bw[kk][2], acc[2], 0, 0, 0);
                    acc[3] = __builtin_amdgcn_mfma_f32_16x16x32_bf16(cc.v, bw[kk][3], acc[3], 0, 0, 0);
                }
            }
            #pragma unroll
            for (int n = 0; n < 4; ++n)
                #pragma unroll
                for (int v = 0; v < 4; ++v)
                    hredLDS[wave - 4][n][v][lane] = acc[n][v];
        }

        __syncthreads();   // A: hredLDS + xred[t&1] ready

        if (wave >= 4) {
            const int v = wave - 4;
            float g0 = bias0, g1 = bias1, g2 = bias2, g3 = bias3;
            const int buf = t & 1;
            #pragma unroll
            for (int w = 0; w < 4; ++w) {
                g0 += xred[buf][w][0][v][lane] + hredLDS[w][0][v][lane];
                g1 += xred[buf][w][1][v][lane] + hredLDS[w][1][v][lane];
                g2 += xred[buf][w][2][v][lane] + hredLDS[w][2][v][lane];
                g3 += xred[buf][w][3][v][lane] + hredLDS[w][3][v][lane];
            }
            float ig = fsig(g0), fg = fsig(g1), gg = ftanhf(g2), og = fsig(g3);
            creg = fg * creg + ig * gg;
            float hval = og * ftanhf(creg);
            hout[(v << 6) + lane] = hval;
            // coherent write-through of h for next step's consumers
            store_hb(hb + (t & 1) * 65536 + cellb * 1024 + cellcolg, f2bfu(hval));
            if (t == T_STEPS - 1) {
                hnp[cellb * 1024 + cellcolg] = hval;
                cnp[cellb * 1024 + cellcolg] = creg;
            } else {
                vm_drain();   // only LLC hb ops in this wave's vm queue
                if (lane == 0)
                    __hip_atomic_fetch_add(cnt, 1, __ATOMIC_RELAXED,
                                           __HIP_MEMORY_SCOPE_AGENT);
            }
        }

        __syncthreads();   // B: hout ready; hredLDS/xred[t&1] consumed

        // ---------- cell waves: off-critical-path tail ----------
        if (wave < 4) {
            float hval = hout[tid];
            outp[((size_t)cellb * 512 + t) * 1024 + cellcolg] = hval;
            if (t < T_STEPS - 1) {
                // x-proj for t+1 from prefetched registers
                f32x4 xacc[4];
                #pragma unroll
                for (int n = 0; n < 4; ++n) xacc[n] = (f32x4){0.f, 0.f, 0.f, 0.f};
                #pragma unroll
                for (int kk = 0; kk < 8; ++kk) {
                    bf16x8 af = cvt8(pa[kk], pb[kk]);
                    xacc[0] = __builtin_amdgcn_mfma_f32_16x16x32_bf16(af, bw[kk][0], xacc[0], 0, 0, 0);
                    xacc[1] = __builtin_amdgcn_mfma_f32_16x16x32_bf16(af, bw[kk][1], xacc[1], 0, 0, 0);
                    xacc[2] = __builtin_amdgcn_mfma_f32_16x16x32_bf16(af, bw[kk][2], xacc[2], 0, 0, 0);
                    xacc[3] = __builtin_amdgcn_mfma_f32_16x16x32_bf16(af, bw[kk][3], xacc[3], 0, 0, 0);
                }
                #pragma unroll
                for (int n = 0; n < 4; ++n)
                    #pragma unroll
                    for (int v = 0; v < 4; ++v)
                        xred[(t + 1) & 1][wave][n][v][lane] = xacc[n][v];
                // prefetch x for t+2 (a full step of latency slack)
                if (t + 2 < T_STEPS) {
                    const float* pn = x + ((size_t)abatch * 512 + (t + 2)) * 1024
                                        + wave * 256 + quad * 8;
                    #pragma unroll
                    for (int kk = 0; kk < 8; ++kk) {
                        pa[kk] = *(const float4*)(pn + kk * 32);
                        pb[kk] = *(const float4*)(pn + kk * 32 + 4);
                    }
                }
            }
        }
    }
}

extern "C" void kernel_launch(void* const* d_in, const int* in_sizes, int n_in,
                              void* d_out, int out_size, void* d_ws, size_t ws_size,
                              hipStream_t stream) {
    const float* x   = (const float*)d_in[0];
    const float* h0  = (const float*)d_in[1];
    const float* c0  = (const float*)d_in[2];
    const float* wih = (const float*)d_in[3];
    const float* whh = (const float*)d_in[4];
    const float* bih = (const float*)d_in[5];
    const float* bhh = (const float*)d_in[6];
    float* out = (float*)d_out;
    // ws layout: hb[2][64][1024] bf16 (256 KB) | cnt[4] ints padded to 128 B each
    unsigned short* hb = (unsigned short*)d_ws;
    int* cnt = (int*)((char*)d_ws + 2 * 65536 * sizeof(unsigned short));
    // monotonic counters must start at 0 every call (ws is poisoned 0xAA)
    hipMemsetAsync(cnt, 0, 4 * 128, stream);
    hipLaunchKernelGGL(lstm_persist, dim3(256), dim3(512), 0, stream,
                       x, h0, c0, wih, whh, bih, bhh, out, hb, cnt);
}